// Round 1
// baseline (349.658 us; speedup 1.0000x reference)
//
#include <hip/hip_runtime.h>
#include <math.h>

#define B 32
#define D 512
#define H 1024
#define G4 4096      // 4*H
#define PCH 32       // plastic i-chunks (32 i's each)
#define GCH 12       // gate k-chunks: 8 cover h-part (1024), 4 cover x-part (512)

// ---------------------------------------------------------------------------
// plastic partials: pp[c][b][h] = sum_{i in chunk c} h0[b,i]*alpha[i,h]*Hebb0[b,i,h]
// grid: B*PCH blocks of 256; each thread owns 4 consecutive h (float4).
__global__ __launch_bounds__(256) void k_plastic(
    const float* __restrict__ h0, const float* __restrict__ alpha,
    const float* __restrict__ hebb, float* __restrict__ pp) {
  int blk = blockIdx.x;
  int b = blk >> 5;          // / PCH
  int c = blk & (PCH - 1);
  int h4 = threadIdx.x * 4;
  int i0 = c * (H / PCH);
  const float* hb = hebb + (size_t)b * H * H;
  float4 acc = make_float4(0.f, 0.f, 0.f, 0.f);
  for (int i = i0; i < i0 + (H / PCH); ++i) {
    float hv = h0[b * H + i];                       // wave-uniform -> scalar load
    float4 a = *(const float4*)(alpha + (size_t)i * H + h4);
    float4 e = *(const float4*)(hb + (size_t)i * H + h4);
    acc.x += hv * a.x * e.x;
    acc.y += hv * a.y * e.y;
    acc.z += hv * a.z * e.z;
    acc.w += hv * a.w * e.w;
  }
  *(float4*)(pp + ((size_t)c * B + b) * H + h4) = acc;
}

// ---------------------------------------------------------------------------
// gate partials: gp[c][b][j] = sum_{i in chunk} in[b,i] * W[i,j]
// chunks 0..7: h0 @ weight_h ; chunks 8..11: x @ weight_x  (128 i's per chunk)
// grid: (16 j-blocks, 12 chunks) x 256 threads; thread owns one j, all 32 b.
__global__ __launch_bounds__(256) void k_gates(
    const float* __restrict__ h0, const float* __restrict__ x,
    const float* __restrict__ wh, const float* __restrict__ wx,
    float* __restrict__ gp) {
  int j = blockIdx.x * 256 + threadIdx.x;
  int c = blockIdx.y;
  float acc[B];
#pragma unroll
  for (int b = 0; b < B; ++b) acc[b] = 0.f;
  if (c < 8) {
    int i0 = c * 128;
    for (int i = i0; i < i0 + 128; ++i) {
      float w = wh[(size_t)i * G4 + j];
#pragma unroll
      for (int b = 0; b < B; ++b) acc[b] += h0[b * H + i] * w;   // uniform -> sgpr
    }
  } else {
    int i0 = (c - 8) * 128;
    for (int i = i0; i < i0 + 128; ++i) {
      float w = wx[(size_t)i * G4 + j];
#pragma unroll
      for (int b = 0; b < B; ++b) acc[b] += x[b * D + i] * w;
    }
  }
#pragma unroll
  for (int b = 0; b < B; ++b) gp[((size_t)c * B + b) * G4 + j] = acc[b];
}

// ---------------------------------------------------------------------------
// combine: reduce partials, activations, write h1 & c1 to out, tanh_g to ws.
__global__ __launch_bounds__(256) void k_combine(
    const float* __restrict__ gp, const float* __restrict__ pp,
    const float* __restrict__ bias, const float* __restrict__ c0,
    float* __restrict__ out, float* __restrict__ tg_out) {
  int t = blockIdx.x * 256 + threadIdx.x;   // 0..B*H-1
  int b = t >> 10;
  int h = t & (H - 1);
  float sf = bias[h], si = bias[H + h], so = bias[2 * H + h], sg = bias[3 * H + h];
#pragma unroll
  for (int c = 0; c < GCH; ++c) {
    const float* g = gp + ((size_t)c * B + b) * G4;
    sf += g[h];
    si += g[H + h];
    so += g[2 * H + h];
    sg += g[3 * H + h];
  }
#pragma unroll
  for (int c = 0; c < PCH; ++c) sg += pp[((size_t)c * B + b) * H + h];
  float fg = 1.f / (1.f + expf(-sf));
  float ig = 1.f / (1.f + expf(-si));
  float og = 1.f / (1.f + expf(-so));
  float tgv = tanhf(sg);
  float c1 = fg * c0[t] + ig * tgv;
  float h1 = og * tanhf(c1);
  out[t] = h1;                 // h1 block
  out[B * H + t] = c1;         // c1 block
  tg_out[t] = tgv;
}

// ---------------------------------------------------------------------------
// Hebb update: out[b,h,i] = clip(Hebb0[b,h,i] + eta*h0[b,h]*tanh_g[b,i], -1, 1)
// grid: B*H blocks (one per (b,h) row), 256 threads x float4 covers i=0..1023.
__global__ __launch_bounds__(256) void k_hebb(
    const float* __restrict__ hebb, const float* __restrict__ h0,
    const float* __restrict__ tg, const float* __restrict__ eta,
    float* __restrict__ out) {
  int blk = blockIdx.x;          // = b*H + h
  int b = blk >> 10;
  float s = eta[0] * h0[blk];
  int t4 = threadIdx.x * 4;
  float4 tv = *(const float4*)(tg + b * H + t4);
  const float* src = hebb + (size_t)blk * H + t4;
  float4 e = *(const float4*)src;
  float4 r;
  r.x = fminf(fmaxf(e.x + s * tv.x, -1.f), 1.f);
  r.y = fminf(fmaxf(e.y + s * tv.y, -1.f), 1.f);
  r.z = fminf(fmaxf(e.z + s * tv.z, -1.f), 1.f);
  r.w = fminf(fmaxf(e.w + s * tv.w, -1.f), 1.f);
  *(float4*)(out + (size_t)blk * H + t4) = r;
}

extern "C" void kernel_launch(void* const* d_in, const int* in_sizes, int n_in,
                              void* d_out, int out_size, void* d_ws, size_t ws_size,
                              hipStream_t stream) {
  const float* x     = (const float*)d_in[0];
  const float* h0    = (const float*)d_in[1];
  const float* c0    = (const float*)d_in[2];
  const float* hebb  = (const float*)d_in[3];
  const float* wh    = (const float*)d_in[4];
  const float* wx    = (const float*)d_in[5];
  const float* bias  = (const float*)d_in[6];
  const float* alpha = (const float*)d_in[7];
  const float* eta   = (const float*)d_in[8];
  float* out = (float*)d_out;
  float* ws  = (float*)d_ws;

  float* pp = ws;                          // [PCH][B][H]   = 1,048,576 floats
  float* gp = pp + (size_t)PCH * B * H;    // [GCH][B][4H]  = 1,572,864 floats
  float* tg = gp + (size_t)GCH * B * G4;   // [B][H]        =    32,768 floats

  k_plastic<<<B * PCH, 256, 0, stream>>>(h0, alpha, hebb, pp);
  k_gates<<<dim3(16, 12), 256, 0, stream>>>(h0, x, wh, wx, gp);
  k_combine<<<(B * H) / 256, 256, 0, stream>>>(gp, pp, bias, c0, out, tg);
  k_hebb<<<B * H, 256, 0, stream>>>(hebb, h0, tg, eta, out + 2 * B * H);
}

// Round 2
// 327.104 us; speedup vs baseline: 1.0689x; 1.0689x over previous
//
#include <hip/hip_runtime.h>
#include <math.h>

#define B 32
#define D 512
#define H 1024
#define G4 4096      // 4*H
#define PCH 32       // plastic i-chunks (32 i's each)
#define GCH 24       // gate k-chunks of 64: 16 cover h-part (1024), 8 cover x-part (512)

// ---------------------------------------------------------------------------
// plastic partials: pp[c][b][h] = sum_{i in chunk c} h0[b,i]*alpha[i,h]*Hebb0[b,i,h]
// grid: B*PCH blocks of 256; each thread owns 4 consecutive h (float4).
__global__ __launch_bounds__(256) void k_plastic(
    const float* __restrict__ h0, const float* __restrict__ alpha,
    const float* __restrict__ hebb, float* __restrict__ pp) {
  int blk = blockIdx.x;
  int b = blk >> 5;          // / PCH
  int c = blk & (PCH - 1);
  int h4 = threadIdx.x * 4;
  int i0 = c * (H / PCH);
  const float* hb = hebb + (size_t)b * H * H;
  float4 acc = make_float4(0.f, 0.f, 0.f, 0.f);
#pragma unroll 8
  for (int i = i0; i < i0 + (H / PCH); ++i) {
    float hv = h0[b * H + i];                       // wave-uniform -> scalar load
    float4 a = *(const float4*)(alpha + (size_t)i * H + h4);
    float4 e = *(const float4*)(hb + (size_t)i * H + h4);
    acc.x += hv * a.x * e.x;
    acc.y += hv * a.y * e.y;
    acc.z += hv * a.z * e.z;
    acc.w += hv * a.w * e.w;
  }
  *(float4*)(pp + ((size_t)c * B + b) * H + h4) = acc;
}

// ---------------------------------------------------------------------------
// gate partials: gp[c][b][j] = sum_{i in chunk c} in[b,i] * W[i,j]
// chunks 0..15: h0 @ weight_h ; chunks 16..23: x @ weight_x  (64 i's per chunk)
// grid: (16 j-blocks, 24 chunks) x 256 threads; thread owns one j, all 32 b.
__global__ __launch_bounds__(256) void k_gates(
    const float* __restrict__ h0, const float* __restrict__ x,
    const float* __restrict__ wh, const float* __restrict__ wx,
    float* __restrict__ gp) {
  int j = blockIdx.x * 256 + threadIdx.x;
  int c = blockIdx.y;
  float acc[B];
#pragma unroll
  for (int b = 0; b < B; ++b) acc[b] = 0.f;
  if (c < 16) {
    int i0 = c * 64;
#pragma unroll 8
    for (int i = i0; i < i0 + 64; ++i) {
      float w = wh[(size_t)i * G4 + j];
#pragma unroll
      for (int b = 0; b < B; ++b) acc[b] += h0[b * H + i] * w;   // uniform -> sgpr
    }
  } else {
    int i0 = (c - 16) * 64;
#pragma unroll 8
    for (int i = i0; i < i0 + 64; ++i) {
      float w = wx[(size_t)i * G4 + j];
#pragma unroll
      for (int b = 0; b < B; ++b) acc[b] += x[b * D + i] * w;
    }
  }
#pragma unroll
  for (int b = 0; b < B; ++b) gp[((size_t)c * B + b) * G4 + j] = acc[b];
}

// ---------------------------------------------------------------------------
// combine: reduce partials, activations, write h1 & c1 to out, tanh_g to ws.
__global__ __launch_bounds__(256) void k_combine(
    const float* __restrict__ gp, const float* __restrict__ pp,
    const float* __restrict__ bias, const float* __restrict__ c0,
    float* __restrict__ out, float* __restrict__ tg_out) {
  int t = blockIdx.x * 256 + threadIdx.x;   // 0..B*H-1
  int b = t >> 10;
  int h = t & (H - 1);
  float sf = bias[h], si = bias[H + h], so = bias[2 * H + h], sg = bias[3 * H + h];
#pragma unroll
  for (int c = 0; c < GCH; ++c) {
    const float* g = gp + ((size_t)c * B + b) * G4;
    sf += g[h];
    si += g[H + h];
    so += g[2 * H + h];
    sg += g[3 * H + h];
  }
#pragma unroll
  for (int c = 0; c < PCH; ++c) sg += pp[((size_t)c * B + b) * H + h];
  float fg = 1.f / (1.f + expf(-sf));
  float ig = 1.f / (1.f + expf(-si));
  float og = 1.f / (1.f + expf(-so));
  float tgv = tanhf(sg);
  float c1 = fg * c0[t] + ig * tgv;
  float h1 = og * tanhf(c1);
  out[t] = h1;                 // h1 block
  out[B * H + t] = c1;         // c1 block
  tg_out[t] = tgv;
}

// ---------------------------------------------------------------------------
// Hebb update: out[b,h,i] = clip(Hebb0[b,h,i] + eta*h0[b,h]*tanh_g[b,i], -1, 1)
// grid: B*128 blocks; each block handles 8 consecutive h-rows of one b.
// tg row loaded once into registers; 8 independent fma+clip chains in flight.
__global__ __launch_bounds__(256) void k_hebb(
    const float* __restrict__ hebb, const float* __restrict__ h0,
    const float* __restrict__ tg, const float* __restrict__ eta,
    float* __restrict__ out) {
  int blk = blockIdx.x;          // 0 .. B*128-1
  int b = blk >> 7;
  int hg = blk & 127;            // h-group of 8 rows
  int t4 = threadIdx.x * 4;
  float4 tv = *(const float4*)(tg + b * H + t4);
  float e = eta[0];
  size_t base = ((size_t)b * H + (size_t)hg * 8) * H + t4;
  const float* src = hebb + base;
  float* dst = out + base;
#pragma unroll
  for (int r = 0; r < 8; ++r) {
    float s = e * h0[b * H + hg * 8 + r];   // wave-uniform scalar
    float4 v = *(const float4*)(src + (size_t)r * H);
    float4 rr;
    rr.x = fminf(fmaxf(v.x + s * tv.x, -1.f), 1.f);
    rr.y = fminf(fmaxf(v.y + s * tv.y, -1.f), 1.f);
    rr.z = fminf(fmaxf(v.z + s * tv.z, -1.f), 1.f);
    rr.w = fminf(fmaxf(v.w + s * tv.w, -1.f), 1.f);
    *(float4*)(dst + (size_t)r * H) = rr;
  }
}

extern "C" void kernel_launch(void* const* d_in, const int* in_sizes, int n_in,
                              void* d_out, int out_size, void* d_ws, size_t ws_size,
                              hipStream_t stream) {
  const float* x     = (const float*)d_in[0];
  const float* h0    = (const float*)d_in[1];
  const float* c0    = (const float*)d_in[2];
  const float* hebb  = (const float*)d_in[3];
  const float* wh    = (const float*)d_in[4];
  const float* wx    = (const float*)d_in[5];
  const float* bias  = (const float*)d_in[6];
  const float* alpha = (const float*)d_in[7];
  const float* eta   = (const float*)d_in[8];
  float* out = (float*)d_out;
  float* ws  = (float*)d_ws;

  float* pp = ws;                          // [PCH][B][H]   = 1,048,576 floats
  float* gp = pp + (size_t)PCH * B * H;    // [GCH][B][4H]  = 3,145,728 floats
  float* tg = gp + (size_t)GCH * B * G4;   // [B][H]        =    32,768 floats

  k_plastic<<<B * PCH, 256, 0, stream>>>(h0, alpha, hebb, pp);
  k_gates<<<dim3(16, GCH), 256, 0, stream>>>(h0, x, wh, wx, gp);
  k_combine<<<(B * H) / 256, 256, 0, stream>>>(gp, pp, bias, c0, out, tg);
  k_hebb<<<B * 128, 256, 0, stream>>>(hebb, h0, tg, eta, out + 2 * B * H);
}